// Round 2
// baseline (271.085 us; speedup 1.0000x reference)
//
#include <hip/hip_runtime.h>
#include <cstdint>
#include <cmath>

#define V_SIZE 50257
#define T_SIZE 2048
#define B_SIZE 512
#define NTHR 1024
#define NWAVE (NTHR / 64)
#define CAND_MAX 1024
#define SPEC_THRESH 10.0f
#define SPEC_MIN 80
#define KOFF 32.0f

// native vector type for __builtin_nontemporal_store (HIP float4 is a class)
typedef float vfloat4 __attribute__((ext_vector_type(4)));

extern "C" __global__ __launch_bounds__(NTHR, 8)
void decode_kernel(const float* __restrict__ logits,
                   const int*   __restrict__ prev,
                   const float* __restrict__ rand_u,
                   const float* __restrict__ tempp,
                   const float* __restrict__ toppp,
                   const float* __restrict__ repp,
                   float* __restrict__ out)
{
    const int row  = blockIdx.x;
    const int tid  = threadIdx.x;
    const int lane = tid & 63;
    const int wid  = tid >> 6;                  // 16 waves of 64

    __shared__ unsigned int bitmap[(V_SIZE + 31) / 32];   // 1571 words
    __shared__ float cval[CAND_MAX];
    __shared__ int   cidx[CAND_MAX];
    __shared__ float rbuf[CAND_MAX];
    __shared__ float redf[NWAVE];
    __shared__ int   redi[NWAVE];
    __shared__ float sM, sZ, sS;
    __shared__ int   sCnt, sSend;

    const float rp   = repp[0];
    const float topp = toppp[0];
    const float temp = fmaxf(tempp[0], 1e-5f);

    const size_t rowoff = (size_t)row * V_SIZE;
    const float* lrow = logits + rowoff;
    const float* urow = rand_u + rowoff;
    float*       orow = out + B_SIZE + rowoff;  // probs after 512 idx floats

    // ---- init LDS ----
    for (int i = tid; i < (V_SIZE + 31) / 32; i += NTHR) bitmap[i] = 0u;
    if (tid == 0) sCnt = 0;
    __syncthreads();

    // ---- membership bitmap of previous tokens ----
    const int4* prow4 = (const int4*)(prev + (size_t)row * T_SIZE);
    for (int i = tid; i < T_SIZE / 4; i += NTHR) {
        int4 t = prow4[i];
        atomicOr(&bitmap[((unsigned)t.x) >> 5], 1u << (t.x & 31));
        atomicOr(&bitmap[((unsigned)t.y) >> 5], 1u << (t.y & 31));
        atomicOr(&bitmap[((unsigned)t.z) >> 5], 1u << (t.z & 31));
        atomicOr(&bitmap[((unsigned)t.w) >> 5], 1u << (t.w & 31));
    }
    __syncthreads();

    // rows are not 16B aligned (V odd) -> per-row head/tail scalars.
    // NOTE: V % 4 == 1, so (512 + row*V) % 4 == (row*V) % 4: the OUTPUT row
    // has the same alignment phase as the logits row -> shared head/nvec/tail.
    const int head  = (4 - (row & 3)) & 3;
    const int nvec  = (V_SIZE - head) >> 2;
    const int tails = head + nvec * 4;          // start of tail scalars
    const float4*  lrow4 = (const float4*)(lrow + head);
    vfloat4*       orow4 = (vfloat4*)(orow + head);

    // ---- pass 1 (stream): penalty + max + fixed-offset expsum + speculative
    //      candidate collect, FUSED with the zero-fill of this row's output.
    //      The zero stores are independent (nontemporal, no reuse) and are
    //      drained by the later __syncthreads barriers long before the final
    //      scatter overwrites the <=51 support slots. This replaces the
    //      ~187 us SDMA hipMemsetAsync that serialized before the kernel. ----
    const vfloat4 z4 = (vfloat4){0.f, 0.f, 0.f, 0.f};
    float lm = -INFINITY, lz = 0.0f;
    auto process1 = [&](float x, int v) {
        unsigned w = bitmap[v >> 5];
        if ((w >> (v & 31)) & 1u) x = (x < 0.0f) ? x * rp : x / rp;
        if (x > SPEC_THRESH) {
            int p = atomicAdd(&sCnt, 1);
            if (p < CAND_MAX) { cval[p] = x; cidx[p] = v; }
        }
        lm = fmaxf(lm, x);
        lz += __expf(x - KOFF);                 // exact rescale later; x<=~20 so no overflow
    };
    if (tid < head) {
        orow[tid] = 0.0f;
        process1(lrow[tid], tid);
    }
    if (tid < V_SIZE - tails) {
        orow[tails + tid] = 0.0f;
        process1(lrow[tails + tid], tails + tid);
    }
    for (int i = tid; i < nvec; i += NTHR) {
        float4 x4 = lrow4[i];
        __builtin_nontemporal_store(z4, &orow4[i]);
        int v = head + i * 4;
        process1(x4.x, v); process1(x4.y, v + 1);
        process1(x4.z, v + 2); process1(x4.w, v + 3);
    }

    // ---- block reduce M ----
    {
        float wm = lm;
        for (int off = 32; off; off >>= 1) wm = fmaxf(wm, __shfl_down(wm, off));
        if (lane == 0) redf[wid] = wm;
    }
    __syncthreads();
    if (tid == 0) {
        float m = redf[0];
        for (int i = 1; i < NWAVE; ++i) m = fmaxf(m, redf[i]);
        sM = m;
    }
    __syncthreads();
    const float M = sM;

    // ---- block reduce S = sum exp(x - KOFF); Z = S * e^(KOFF - M) ----
    {
        float wz = lz;
        for (int off = 32; off; off >>= 1) wz += __shfl_down(wz, off);
        if (lane == 0) redf[wid] = wz;
    }
    __syncthreads();
    if (tid == 0) {
        float s = 0.0f;
        for (int i = 0; i < NWAVE; ++i) s += redf[i];
        sZ = s * expf(KOFF - M);
    }
    __syncthreads();
    const float Z = sZ;

    // ---- candidate set: speculative {x > 10}; bisection fallback (≈never) ----
    int cnt = sCnt;                              // ordered by the barriers above
    int C;
    if (cnt >= SPEC_MIN && cnt <= CAND_MAX) {
        C = cnt;                                 // exact value-prefix of the row
    } else {
        auto count_pass = [&](float thr) -> int {
            __syncthreads();
            if (tid == 0) sCnt = 0;
            __syncthreads();
            int local = 0;
            for (int v = tid; v < V_SIZE; v += NTHR) {
                float x = lrow[v];
                unsigned w = bitmap[v >> 5];
                if ((w >> (v & 31)) & 1u) x = (x < 0.0f) ? x * rp : x / rp;
                if (x > thr) local++;
            }
            if (local) atomicAdd(&sCnt, local);
            __syncthreads();
            return sCnt;
        };
        float a = -200.0f, b = 200.0f, thr = 0.0f;
        int c = 0;
        for (int it = 0; it < 40; ++it) {
            thr = 0.5f * (a + b);
            c = count_pass(thr);
            if (c < SPEC_MIN)       b = thr;
            else if (c > CAND_MAX)  a = thr;
            else break;
        }
        if (c < SPEC_MIN) thr = a;               // last side with enough mass
        __syncthreads();
        if (tid == 0) sCnt = 0;
        __syncthreads();
        for (int v = tid; v < V_SIZE; v += NTHR) {
            float x = lrow[v];
            unsigned w = bitmap[v >> 5];
            if ((w >> (v & 31)) & 1u) x = (x < 0.0f) ? x * rp : x / rp;
            if (x > thr) {
                int p = atomicAdd(&sCnt, 1);
                if (p < CAND_MAX) { cval[p] = x; cidx[p] = v; }
            }
        }
        __syncthreads();
        C = min(sCnt, CAND_MAX);
    }

    // ---- bitonic sort candidates: descending value, tie -> ascending index ----
    int n = 1; while (n < C) n <<= 1;            // n in [128,1024]
    for (int i = C + tid; i < n; i += NTHR) { cval[i] = -INFINITY; cidx[i] = 0x7FFFFFFF; }
    __syncthreads();
    for (int k = 2; k <= n; k <<= 1) {
        for (int j = k >> 1; j > 0; j >>= 1) {
            for (int i = tid; i < n; i += NTHR) {
                int l = i ^ j;
                if (l > i) {
                    float vi = cval[i], vl = cval[l];
                    int   ii = cidx[i], il = cidx[l];
                    bool lFirst = (vl > vi) || (vl == vi && il < ii);
                    bool asc = ((i & k) == 0);
                    if (lFirst == asc) {
                        cval[i] = vl; cval[l] = vi;
                        cidx[i] = il; cidx[l] = ii;
                    }
                }
            }
            __syncthreads();
        }
    }

    // ---- precompute softmax terms in parallel (same values/order as the
    //      serial loop used; keeps the tid==0 decision loop add/compare-only) ----
    for (int i = tid; i < C; i += NTHR)
        rbuf[i] = expf(cval[i] - M) / Z;
    __syncthreads();

    // ---- serial decision: top-p prefix m, top-50 pivot tie-run e ----
    if (tid == 0) {
        float cum = 0.0f;
        int m = 0;
        float vp = cval[min(49, C - 1)];
        for (int i = 0; i < C; ++i) {
            cum += rbuf[i];
            if (i > 0 && cum > topp) break;      // suffix removed; m final
            m = i;
            if (m >= 49 && cval[i] < vp) break;  // past pivot tie-run; support=e
        }
        int send;
        if (m >= 49) {
            int e = 49;
            while (e + 1 < C && cval[e + 1] == vp) ++e;
            send = (m < e) ? m : e;
        } else {
            send = m;
        }
        sSend = send;
    }
    __syncthreads();

    // ---- final softmax over support (temperature applied), scatter, sample ----
    const int send = sSend;
    const float v0 = cval[0];                    // row max (position 0)
    for (int i = tid; i <= send; i += NTHR)
        rbuf[i] = expf(cval[i] / temp - v0 / temp);
    __syncthreads();
    if (tid == 0) {
        float S = 0.0f;
        for (int i = 0; i <= send; ++i) S += rbuf[i];
        sS = S;
    }
    __syncthreads();
    const float S = sS;

    float bestr = -1.0f;
    int   besti = 0x7FFFFFFF;
    for (int i = tid; i <= send; i += NTHR) {
        float p = rbuf[i] / S;
        int v = cidx[i];
        orow[v] = p;                             // zeros were streamed in pass 1
        float q = -logf(urow[v]);
        float r = p / q;
        if (r > bestr || (r == bestr && v < besti)) { bestr = r; besti = v; }
    }
    for (int off = 32; off; off >>= 1) {
        float r2 = __shfl_down(bestr, off);
        int   i2 = __shfl_down(besti, off);
        if (r2 > bestr || (r2 == bestr && i2 < besti)) { bestr = r2; besti = i2; }
    }
    if (lane == 0) { redf[wid] = bestr; redi[wid] = besti; }
    __syncthreads();
    if (tid == 0) {
        float br = redf[0]; int bi = redi[0];
        for (int i = 1; i < NWAVE; ++i) {
            if (redf[i] > br || (redf[i] == br && redi[i] < bi)) { br = redf[i]; bi = redi[i]; }
        }
        out[row] = (float)bi;                    // idx as f32 (exact for < 2^24)
    }
}

extern "C" void kernel_launch(void* const* d_in, const int* in_sizes, int n_in,
                              void* d_out, int out_size, void* d_ws, size_t ws_size,
                              hipStream_t stream) {
    const float* logits = (const float*)d_in[0];
    const int*   prev   = (const int*)d_in[1];
    const float* rand_u = (const float*)d_in[2];
    const float* tempp  = (const float*)d_in[3];
    const float* toppp  = (const float*)d_in[4];
    const float* repp   = (const float*)d_in[5];
    float* out = (float*)d_out;

    // The kernel now zero-fills the idx area (all 512 rows write out[row])
    // and each row's prob region (fused NT stores in pass 1). Only zero any
    // padding tail beyond the region the kernel covers (usually zero bytes).
    const size_t covered = (size_t)B_SIZE + (size_t)B_SIZE * V_SIZE;
    if ((size_t)out_size > covered) {
        (void)hipMemsetAsync(out + covered, 0,
                             ((size_t)out_size - covered) * sizeof(float), stream);
    }

    hipLaunchKernelGGL(decode_kernel, dim3(B_SIZE), dim3(NTHR), 0, stream,
                       logits, prev, rand_u, tempp, toppp, repp, out);
}

// Round 4
// 264.291 us; speedup vs baseline: 1.0257x; 1.0257x over previous
//
#include <hip/hip_runtime.h>
#include <cstdint>
#include <cmath>

#define V_SIZE 50257
#define T_SIZE 2048
#define B_SIZE 512
#define CAND_MAX 1024
#define SPEC_THRESH 10.0f
#define SPEC_MIN 80
#define KOFF 32.0f

#define NTHR1 1024
#define NWAVE1 (NTHR1 / 64)
#define NTHR2 512
#define NWAVE2 (NTHR2 / 64)

#define BM_WORDS ((V_SIZE + 31) / 32)

// K1->K2 scratch: tail 2050 floats of each row's own prob region
// (zeroed by the big memset, rewritten by K1, consumed + re-zeroed by K2
//  before the final prob scatter).
#define SCR_BASE (V_SIZE - (2 * CAND_MAX + 2))
#define SCR_VALS (SCR_BASE)
#define SCR_IDX  (SCR_BASE + CAND_MAX)
#define SCR_CNT  (SCR_BASE + 2 * CAND_MAX)
#define SCR_STOT (SCR_BASE + 2 * CAND_MAX + 1)

// ---------------------------------------------------------------------------
// K1: pure stream. Plain expsum + speculative candidates (plain x > 10).
// Repetition penalty handled OFF the hot path:
//   - dedup'd correction  sum += e^(x'-K) - e^(x-K)  over unique prev tokens
//   - post-fix of collected candidates that are in the prev set
// Valid because penalty only DECREASES a logit: final>10 => plain>10 => collected.
// ---------------------------------------------------------------------------
extern "C" __global__ __launch_bounds__(NTHR1, 8)
void pass1_kernel(const float* __restrict__ logits,
                  const int*   __restrict__ prev,
                  const float* __restrict__ repp,
                  float* __restrict__ out)
{
    const int row  = blockIdx.x;
    const int tid  = threadIdx.x;
    const int lane = tid & 63;
    const int wid  = tid >> 6;

    __shared__ unsigned int bitmap[BM_WORDS];
    __shared__ float cval[CAND_MAX];
    __shared__ int   cidx[CAND_MAX];
    __shared__ float redf[NWAVE1];
    __shared__ int   sCnt;

    const float rp = repp[0];
    const float* lrow = logits + (size_t)row * V_SIZE;
    float*       orow = out + B_SIZE + (size_t)row * V_SIZE;

    for (int i = tid; i < BM_WORDS; i += NTHR1) bitmap[i] = 0u;
    if (tid == 0) sCnt = 0;
    __syncthreads();

    // prev membership bitmap + dedup'd expsum correction (scattered loads
    // overlap with the stream below; only ~2 tokens/thread).
    const int* prow = prev + (size_t)row * T_SIZE;
    float corr = 0.0f;
    for (int i = tid; i < T_SIZE; i += NTHR1) {
        int v = prow[i];
        unsigned bit = 1u << (v & 31);
        unsigned old = atomicOr(&bitmap[((unsigned)v) >> 5], bit);
        if (!(old & bit)) {                    // first setter owns the correction
            float x  = lrow[v];
            float xp = (x < 0.0f) ? x * rp : x / rp;   // exact division
            corr += __expf(xp - KOFF) - __expf(x - KOFF);
        }
    }

    // plain stream (no bitmap reads, no penalty, no max)
    const int head  = (4 - (row & 3)) & 3;     // V%4==1 -> row*V mod 4 == row mod 4
    const int nvec  = (V_SIZE - head) >> 2;
    const int tails = head + nvec * 4;
    const float4* lrow4 = (const float4*)(lrow + head);

    float lz0 = 0.0f, lz1 = 0.0f;
    auto collect = [&](float x, int v) {
        if (x > SPEC_THRESH) {
            int p = atomicAdd(&sCnt, 1);
            if (p < CAND_MAX) { cval[p] = x; cidx[p] = v; }
        }
    };
    if (tid < head) {
        float x = lrow[tid];
        collect(x, tid);
        lz0 += __expf(x - KOFF);
    }
    if (tid < V_SIZE - tails) {
        float x = lrow[tails + tid];
        collect(x, tails + tid);
        lz0 += __expf(x - KOFF);
    }
    for (int i = tid; i < nvec; i += NTHR1) {
        float4 x4 = lrow4[i];
        int v = head + i * 4;
        collect(x4.x, v);     collect(x4.y, v + 1);
        collect(x4.z, v + 2); collect(x4.w, v + 3);
        lz0 += __expf(x4.x - KOFF) + __expf(x4.z - KOFF);
        lz1 += __expf(x4.y - KOFF) + __expf(x4.w - KOFF);
    }
    __syncthreads();                           // bitmap + candidate list complete

    // fix penalties on collected candidates (C*4% ~ a dozen hits)
    const int C = min(sCnt, CAND_MAX);
    for (int i = tid; i < C; i += NTHR1) {
        int v = cidx[i];
        if ((bitmap[((unsigned)v) >> 5] >> (v & 31)) & 1u) {
            float x = cval[i];
            cval[i] = (x < 0.0f) ? x * rp : x / rp;
        }
    }

    // reduce corrected plain sum
    float wz = lz0 + lz1 + corr;
    for (int off = 32; off; off >>= 1) wz += __shfl_down(wz, off);
    if (lane == 0) redf[wid] = wz;
    __syncthreads();

    // scratch out (same-thread i-ranges as the fix loop -> no extra barrier)
    for (int i = tid; i < C; i += NTHR1) {
        orow[SCR_VALS + i] = cval[i];
        orow[SCR_IDX  + i] = __int_as_float(cidx[i]);
    }
    if (tid == 0) {
        float s = 0.0f;
        for (int i = 0; i < NWAVE1; ++i) s += redf[i];
        orow[SCR_CNT]  = __int_as_float(sCnt);   // raw count (may exceed CAND_MAX)
        orow[SCR_STOT] = s;                      // sum exp(final - KOFF), exact
    }
}

// ---------------------------------------------------------------------------
// K2: candidate-only work. M/Z, bitonic sort, top-p/top-k decision, final
// softmax scatter + gumbel-argmax sample. Bisection fallback self-contained.
// ---------------------------------------------------------------------------
extern "C" __global__ __launch_bounds__(NTHR2, 8)
void decide_kernel(const float* __restrict__ logits,
                   const int*   __restrict__ prev,
                   const float* __restrict__ rand_u,
                   const float* __restrict__ tempp,
                   const float* __restrict__ toppp,
                   const float* __restrict__ repp,
                   float* __restrict__ out)
{
    const int row  = blockIdx.x;
    const int tid  = threadIdx.x;
    const int lane = tid & 63;
    const int wid  = tid >> 6;

    __shared__ unsigned int bitmap[BM_WORDS];   // fallback only
    __shared__ float cval[CAND_MAX];
    __shared__ int   cidx[CAND_MAX];
    __shared__ float rbuf[CAND_MAX];
    __shared__ float redf[NWAVE2];
    __shared__ int   redi[NWAVE2];
    __shared__ float sM, sZ, sS;
    __shared__ int   sCnt, sSend;

    const float rp   = repp[0];
    const float topp = toppp[0];
    const float temp = fmaxf(tempp[0], 1e-5f);

    const size_t rowoff = (size_t)row * V_SIZE;
    const float* lrow = logits + rowoff;
    const float* urow = rand_u + rowoff;
    float*       orow = out + B_SIZE + rowoff;

    const int   cntRaw = __float_as_int(orow[SCR_CNT]);
    const float stot   = orow[SCR_STOT];

    int C = 0;
    float M = 0.0f, Z = 1.0f;
    bool ok = (cntRaw >= SPEC_MIN && cntRaw <= CAND_MAX);   // block-uniform

    if (ok) {
        C = cntRaw;
        float lm = -INFINITY;
        for (int i = tid; i < C; i += NTHR2) {
            float v = orow[SCR_VALS + i];
            cval[i] = v;
            cidx[i] = __float_as_int(orow[SCR_IDX + i]);
            lm = fmaxf(lm, v);
        }
        for (int off = 32; off; off >>= 1) lm = fmaxf(lm, __shfl_down(lm, off));
        if (lane == 0) redf[wid] = lm;
        __syncthreads();
        if (tid == 0) {
            float m = redf[0];
            for (int i = 1; i < NWAVE2; ++i) m = fmaxf(m, redf[i]);
            sM = m;
        }
        __syncthreads();
        M = sM;
        Z = stot * expf(KOFF - M);
        // guard: exactness requires the true row max to be a candidate, which
        // holds iff the fixed candidate max clears the plain threshold.
        if (!(M > SPEC_THRESH)) ok = false;     // still block-uniform
    }

    if (!ok) {
        // ---- fallback: full recompute with penalty inline (≈never) ----
        for (int i = tid; i < BM_WORDS; i += NTHR2) bitmap[i] = 0u;
        __syncthreads();
        const int* prow = prev + (size_t)row * T_SIZE;
        for (int i = tid; i < T_SIZE; i += NTHR2) {
            int v = prow[i];
            atomicOr(&bitmap[((unsigned)v) >> 5], 1u << (v & 31));
        }
        __syncthreads();

        float lm = -INFINITY, lz = 0.0f;
        for (int v = tid; v < V_SIZE; v += NTHR2) {
            float x = lrow[v];
            if ((bitmap[((unsigned)v) >> 5] >> (v & 31)) & 1u)
                x = (x < 0.0f) ? x * rp : x / rp;
            lm = fmaxf(lm, x);
            lz += __expf(x - KOFF);
        }
        {
            float wm = lm;
            for (int off = 32; off; off >>= 1) wm = fmaxf(wm, __shfl_down(wm, off));
            if (lane == 0) redf[wid] = wm;
        }
        __syncthreads();
        if (tid == 0) {
            float m = redf[0];
            for (int i = 1; i < NWAVE2; ++i) m = fmaxf(m, redf[i]);
            sM = m;
        }
        __syncthreads();
        M = sM;
        {
            float wz = lz;
            for (int off = 32; off; off >>= 1) wz += __shfl_down(wz, off);
            if (lane == 0) redf[wid] = wz;
        }
        __syncthreads();
        if (tid == 0) {
            float s = 0.0f;
            for (int i = 0; i < NWAVE2; ++i) s += redf[i];
            sZ = s * expf(KOFF - M);
        }
        __syncthreads();
        Z = sZ;

        auto count_pass = [&](float thr) -> int {
            __syncthreads();
            if (tid == 0) sCnt = 0;
            __syncthreads();
            int local = 0;
            for (int v = tid; v < V_SIZE; v += NTHR2) {
                float x = lrow[v];
                if ((bitmap[((unsigned)v) >> 5] >> (v & 31)) & 1u)
                    x = (x < 0.0f) ? x * rp : x / rp;
                if (x > thr) local++;
            }
            if (local) atomicAdd(&sCnt, local);
            __syncthreads();
            return sCnt;
        };
        float a = -200.0f, b = 200.0f, thr = 0.0f;
        int c = 0;
        for (int it = 0; it < 40; ++it) {
            thr = 0.5f * (a + b);
            c = count_pass(thr);
            if (c < SPEC_MIN)       b = thr;
            else if (c > CAND_MAX)  a = thr;
            else break;
        }
        if (c < SPEC_MIN) thr = a;
        __syncthreads();
        if (tid == 0) sCnt = 0;
        __syncthreads();
        for (int v = tid; v < V_SIZE; v += NTHR2) {
            float x = lrow[v];
            if ((bitmap[((unsigned)v) >> 5] >> (v & 31)) & 1u)
                x = (x < 0.0f) ? x * rp : x / rp;
            if (x > thr) {
                int p = atomicAdd(&sCnt, 1);
                if (p < CAND_MAX) { cval[p] = x; cidx[p] = v; }
            }
        }
        __syncthreads();
        C = min(sCnt, CAND_MAX);
    }

    // ---- re-zero the scratch tail (before the final prob scatter) ----
    for (int i = tid; i < 2 * CAND_MAX + 2; i += NTHR2)
        orow[SCR_BASE + i] = 0.0f;

    // ---- bitonic sort: descending value, tie -> ascending index ----
    int n = 1; while (n < C) n <<= 1;
    for (int i = C + tid; i < n; i += NTHR2) { cval[i] = -INFINITY; cidx[i] = 0x7FFFFFFF; }
    __syncthreads();
    for (int k = 2; k <= n; k <<= 1) {
        for (int j = k >> 1; j > 0; j >>= 1) {
            for (int i = tid; i < n; i += NTHR2) {
                int l = i ^ j;
                if (l > i) {
                    float vi = cval[i], vl = cval[l];
                    int   ii = cidx[i], il = cidx[l];
                    bool lFirst = (vl > vi) || (vl == vi && il < ii);
                    bool asc = ((i & k) == 0);
                    if (lFirst == asc) {
                        cval[i] = vl; cval[l] = vi;
                        cidx[i] = il; cidx[l] = ii;
                    }
                }
            }
            __syncthreads();
        }
    }

    // ---- parallel softmax terms; serial decision is add/compare-only ----
    for (int i = tid; i < C; i += NTHR2)
        rbuf[i] = expf(cval[i] - M) / Z;
    __syncthreads();

    if (tid == 0) {
        float cum = 0.0f;
        int m = 0;
        float vp = cval[min(49, C - 1)];
        for (int i = 0; i < C; ++i) {
            cum += rbuf[i];
            if (i > 0 && cum > topp) break;      // suffix removed; m final
            m = i;
            if (m >= 49 && cval[i] < vp) break;  // past pivot tie-run
        }
        int send;
        if (m >= 49) {
            int e = 49;
            while (e + 1 < C && cval[e + 1] == vp) ++e;
            send = (m < e) ? m : e;
        } else {
            send = m;
        }
        sSend = send;
    }
    __syncthreads();

    // ---- final softmax over support, scatter, sample ----
    const int send = sSend;
    const float v0 = cval[0];
    for (int i = tid; i <= send; i += NTHR2)
        rbuf[i] = expf(cval[i] / temp - v0 / temp);
    __syncthreads();
    if (tid == 0) {
        float S = 0.0f;
        for (int i = 0; i <= send; ++i) S += rbuf[i];
        sS = S;
    }
    __syncthreads();
    const float S = sS;

    float bestr = -1.0f;
    int   besti = 0x7FFFFFFF;
    for (int i = tid; i <= send; i += NTHR2) {
        float p = rbuf[i] / S;
        int v = cidx[i];
        orow[v] = p;                             // memset + scratch re-zero did the rest
        float q = -logf(urow[v]);
        float r = p / q;
        if (r > bestr || (r == bestr && v < besti)) { bestr = r; besti = v; }
    }
    for (int off = 32; off; off >>= 1) {
        float r2 = __shfl_down(bestr, off);
        int   i2 = __shfl_down(besti, off);
        if (r2 > bestr || (r2 == bestr && i2 < besti)) { bestr = r2; besti = i2; }
    }
    if (lane == 0) { redf[wid] = bestr; redi[wid] = besti; }
    __syncthreads();
    if (tid == 0) {
        float br = redf[0]; int bi = redi[0];
        for (int i = 1; i < NWAVE2; ++i) {
            if (redf[i] > br || (redf[i] == br && redi[i] < bi)) { br = redf[i]; bi = redi[i]; }
        }
        out[row] = (float)bi;
    }
}

extern "C" void kernel_launch(void* const* d_in, const int* in_sizes, int n_in,
                              void* d_out, int out_size, void* d_ws, size_t ws_size,
                              hipStream_t stream) {
    const float* logits = (const float*)d_in[0];
    const int*   prev   = (const int*)d_in[1];
    const float* rand_u = (const float*)d_in[2];
    const float* tempp  = (const float*)d_in[3];
    const float* toppp  = (const float*)d_in[4];
    const float* repp   = (const float*)d_in[5];
    float* out = (float*)d_out;

    // Full-buffer zero via driver blit (measured ~free vs. in-kernel NT fill).
    (void)hipMemsetAsync(d_out, 0, (size_t)out_size * sizeof(float), stream);

    hipLaunchKernelGGL(pass1_kernel, dim3(B_SIZE), dim3(NTHR1), 0, stream,
                       logits, prev, repp, out);
    hipLaunchKernelGGL(decide_kernel, dim3(B_SIZE), dim3(NTHR2), 0, stream,
                       logits, prev, rand_u, tempp, toppp, repp, out);
}

// Round 5
// 255.619 us; speedup vs baseline: 1.0605x; 1.0339x over previous
//
#include <hip/hip_runtime.h>
#include <cstdint>
#include <cmath>

#define V_SIZE 50257
#define T_SIZE 2048
#define B_SIZE 512
#define CAND_MAX 1024
#define SPEC_THRESH 10.0f
#define SPEC_MIN 80
#define KOFF 32.0f

#define NTHR1 1024
#define NWAVE1 (NTHR1 / 64)
#define NTHR2 512
#define NWAVE2 (NTHR2 / 64)

#define BM_WORDS ((V_SIZE + 31) / 32)

// K1->K2 scratch: tail 2050 floats of each row's own prob region
// (zeroed by the memset, rewritten by K1, consumed + re-zeroed by K2
//  before the final prob scatter).
#define SCR_BASE (V_SIZE - (2 * CAND_MAX + 2))
#define SCR_VALS (SCR_BASE)
#define SCR_IDX  (SCR_BASE + CAND_MAX)
#define SCR_CNT  (SCR_BASE + 2 * CAND_MAX)
#define SCR_STOT (SCR_BASE + 2 * CAND_MAX + 1)

// ---------------------------------------------------------------------------
// K1: pure stream. Plain expsum + speculative candidates (plain x > 10).
// Repetition penalty handled OFF the hot path:
//   - dedup'd correction  sum += e^(x'-K) - e^(x-K)  over unique prev tokens
//   - post-fix of collected candidates that are in the prev set
// Valid because penalty only DECREASES a logit: final>10 => plain>10 => collected.
// ---------------------------------------------------------------------------
extern "C" __global__ __launch_bounds__(NTHR1, 8)
void pass1_kernel(const float* __restrict__ logits,
                  const int*   __restrict__ prev,
                  const float* __restrict__ repp,
                  float* __restrict__ out)
{
    const int row  = blockIdx.x;
    const int tid  = threadIdx.x;
    const int lane = tid & 63;
    const int wid  = tid >> 6;

    __shared__ unsigned int bitmap[BM_WORDS];
    __shared__ float cval[CAND_MAX];
    __shared__ int   cidx[CAND_MAX];
    __shared__ float redf[NWAVE1];
    __shared__ int   sCnt;

    const float rp = repp[0];
    const float* lrow = logits + (size_t)row * V_SIZE;
    float*       orow = out + B_SIZE + (size_t)row * V_SIZE;

    for (int i = tid; i < BM_WORDS; i += NTHR1) bitmap[i] = 0u;
    if (tid == 0) sCnt = 0;
    __syncthreads();

    // prev membership bitmap + dedup'd expsum correction (scattered loads
    // overlap with the stream below; only ~2 tokens/thread).
    const int* prow = prev + (size_t)row * T_SIZE;
    float corr = 0.0f;
    for (int i = tid; i < T_SIZE; i += NTHR1) {
        int v = prow[i];
        unsigned bit = 1u << (v & 31);
        unsigned old = atomicOr(&bitmap[((unsigned)v) >> 5], bit);
        if (!(old & bit)) {                    // first setter owns the correction
            float x  = lrow[v];
            float xp = (x < 0.0f) ? x * rp : x / rp;   // exact division
            corr += __expf(xp - KOFF) - __expf(x - KOFF);
        }
    }

    // plain stream (no bitmap reads, no penalty, no max)
    const int head  = (4 - (row & 3)) & 3;     // V%4==1 -> row*V mod 4 == row mod 4
    const int nvec  = (V_SIZE - head) >> 2;
    const int tails = head + nvec * 4;
    const float4* lrow4 = (const float4*)(lrow + head);

    float lz0 = 0.0f, lz1 = 0.0f;
    auto collect = [&](float x, int v) {
        if (x > SPEC_THRESH) {
            int p = atomicAdd(&sCnt, 1);
            if (p < CAND_MAX) { cval[p] = x; cidx[p] = v; }
        }
    };
    if (tid < head) {
        float x = lrow[tid];
        collect(x, tid);
        lz0 += __expf(x - KOFF);
    }
    if (tid < V_SIZE - tails) {
        float x = lrow[tails + tid];
        collect(x, tails + tid);
        lz0 += __expf(x - KOFF);
    }
    for (int i = tid; i < nvec; i += NTHR1) {
        float4 x4 = lrow4[i];
        int v = head + i * 4;
        collect(x4.x, v);     collect(x4.y, v + 1);
        collect(x4.z, v + 2); collect(x4.w, v + 3);
        lz0 += __expf(x4.x - KOFF) + __expf(x4.z - KOFF);
        lz1 += __expf(x4.y - KOFF) + __expf(x4.w - KOFF);
    }
    __syncthreads();                           // bitmap + candidate list complete

    // fix penalties on collected candidates (C*4% ~ a dozen hits)
    const int C = min(sCnt, CAND_MAX);
    for (int i = tid; i < C; i += NTHR1) {
        int v = cidx[i];
        if ((bitmap[((unsigned)v) >> 5] >> (v & 31)) & 1u) {
            float x = cval[i];
            cval[i] = (x < 0.0f) ? x * rp : x / rp;
        }
    }

    // reduce corrected plain sum
    float wz = lz0 + lz1 + corr;
    for (int off = 32; off; off >>= 1) wz += __shfl_down(wz, off);
    if (lane == 0) redf[wid] = wz;
    __syncthreads();

    // scratch out (same-thread i-ranges as the fix loop -> no extra barrier)
    for (int i = tid; i < C; i += NTHR1) {
        orow[SCR_VALS + i] = cval[i];
        orow[SCR_IDX  + i] = __int_as_float(cidx[i]);
    }
    if (tid == 0) {
        float s = 0.0f;
        for (int i = 0; i < NWAVE1; ++i) s += redf[i];
        orow[SCR_CNT]  = __int_as_float(sCnt);   // raw count (may exceed CAND_MAX)
        orow[SCR_STOT] = s;                      // sum exp(final - KOFF), exact
    }
}

// ---------------------------------------------------------------------------
// K2: candidate-only work. M/Z, bitonic sort, top-p/top-k decision, final
// softmax scatter + gumbel-argmax sample. Bisection fallback self-contained.
// ---------------------------------------------------------------------------
extern "C" __global__ __launch_bounds__(NTHR2, 8)
void decide_kernel(const float* __restrict__ logits,
                   const int*   __restrict__ prev,
                   const float* __restrict__ rand_u,
                   const float* __restrict__ tempp,
                   const float* __restrict__ toppp,
                   const float* __restrict__ repp,
                   float* __restrict__ out)
{
    const int row  = blockIdx.x;
    const int tid  = threadIdx.x;
    const int lane = tid & 63;
    const int wid  = tid >> 6;

    __shared__ unsigned int bitmap[BM_WORDS];   // fallback only
    __shared__ float cval[CAND_MAX];
    __shared__ int   cidx[CAND_MAX];
    __shared__ float rbuf[CAND_MAX];
    __shared__ float redf[NWAVE2];
    __shared__ int   redi[NWAVE2];
    __shared__ float sM, sZ, sS;
    __shared__ int   sCnt, sSend;

    const float rp   = repp[0];
    const float topp = toppp[0];
    const float temp = fmaxf(tempp[0], 1e-5f);

    const size_t rowoff = (size_t)row * V_SIZE;
    const float* lrow = logits + rowoff;
    const float* urow = rand_u + rowoff;
    float*       orow = out + B_SIZE + rowoff;

    const int   cntRaw = __float_as_int(orow[SCR_CNT]);
    const float stot   = orow[SCR_STOT];

    int C = 0;
    float M = 0.0f, Z = 1.0f;
    bool ok = (cntRaw >= SPEC_MIN && cntRaw <= CAND_MAX);   // block-uniform

    if (ok) {
        C = cntRaw;
        float lm = -INFINITY;
        for (int i = tid; i < C; i += NTHR2) {
            float v = orow[SCR_VALS + i];
            cval[i] = v;
            cidx[i] = __float_as_int(orow[SCR_IDX + i]);
            lm = fmaxf(lm, v);
        }
        for (int off = 32; off; off >>= 1) lm = fmaxf(lm, __shfl_down(lm, off));
        if (lane == 0) redf[wid] = lm;
        __syncthreads();
        if (tid == 0) {
            float m = redf[0];
            for (int i = 1; i < NWAVE2; ++i) m = fmaxf(m, redf[i]);
            sM = m;
        }
        __syncthreads();
        M = sM;
        Z = stot * expf(KOFF - M);
        // guard: exactness requires the true row max to be a candidate, which
        // holds iff the fixed candidate max clears the plain threshold.
        if (!(M > SPEC_THRESH)) ok = false;     // still block-uniform
    }

    if (!ok) {
        // ---- fallback: full recompute with penalty inline (≈never) ----
        for (int i = tid; i < BM_WORDS; i += NTHR2) bitmap[i] = 0u;
        __syncthreads();
        const int* prow = prev + (size_t)row * T_SIZE;
        for (int i = tid; i < T_SIZE; i += NTHR2) {
            int v = prow[i];
            atomicOr(&bitmap[((unsigned)v) >> 5], 1u << (v & 31));
        }
        __syncthreads();

        float lm = -INFINITY, lz = 0.0f;
        for (int v = tid; v < V_SIZE; v += NTHR2) {
            float x = lrow[v];
            if ((bitmap[((unsigned)v) >> 5] >> (v & 31)) & 1u)
                x = (x < 0.0f) ? x * rp : x / rp;
            lm = fmaxf(lm, x);
            lz += __expf(x - KOFF);
        }
        {
            float wm = lm;
            for (int off = 32; off; off >>= 1) wm = fmaxf(wm, __shfl_down(wm, off));
            if (lane == 0) redf[wid] = wm;
        }
        __syncthreads();
        if (tid == 0) {
            float m = redf[0];
            for (int i = 1; i < NWAVE2; ++i) m = fmaxf(m, redf[i]);
            sM = m;
        }
        __syncthreads();
        M = sM;
        {
            float wz = lz;
            for (int off = 32; off; off >>= 1) wz += __shfl_down(wz, off);
            if (lane == 0) redf[wid] = wz;
        }
        __syncthreads();
        if (tid == 0) {
            float s = 0.0f;
            for (int i = 0; i < NWAVE2; ++i) s += redf[i];
            sZ = s * expf(KOFF - M);
        }
        __syncthreads();
        Z = sZ;

        auto count_pass = [&](float thr) -> int {
            __syncthreads();
            if (tid == 0) sCnt = 0;
            __syncthreads();
            int local = 0;
            for (int v = tid; v < V_SIZE; v += NTHR2) {
                float x = lrow[v];
                if ((bitmap[((unsigned)v) >> 5] >> (v & 31)) & 1u)
                    x = (x < 0.0f) ? x * rp : x / rp;
                if (x > thr) local++;
            }
            if (local) atomicAdd(&sCnt, local);
            __syncthreads();
            return sCnt;
        };
        float a = -200.0f, b = 200.0f, thr = 0.0f;
        int c = 0;
        for (int it = 0; it < 40; ++it) {
            thr = 0.5f * (a + b);
            c = count_pass(thr);
            if (c < SPEC_MIN)       b = thr;
            else if (c > CAND_MAX)  a = thr;
            else break;
        }
        if (c < SPEC_MIN) thr = a;
        __syncthreads();
        if (tid == 0) sCnt = 0;
        __syncthreads();
        for (int v = tid; v < V_SIZE; v += NTHR2) {
            float x = lrow[v];
            if ((bitmap[((unsigned)v) >> 5] >> (v & 31)) & 1u)
                x = (x < 0.0f) ? x * rp : x / rp;
            if (x > thr) {
                int p = atomicAdd(&sCnt, 1);
                if (p < CAND_MAX) { cval[p] = x; cidx[p] = v; }
            }
        }
        __syncthreads();
        C = min(sCnt, CAND_MAX);
    }

    // ---- re-zero the scratch tail (before the final prob scatter) ----
    for (int i = tid; i < 2 * CAND_MAX + 2; i += NTHR2)
        orow[SCR_BASE + i] = 0.0f;

    // ---- bitonic sort: descending value, tie -> ascending index ----
    int n = 1; while (n < C) n <<= 1;
    for (int i = C + tid; i < n; i += NTHR2) { cval[i] = -INFINITY; cidx[i] = 0x7FFFFFFF; }
    __syncthreads();
    for (int k = 2; k <= n; k <<= 1) {
        for (int j = k >> 1; j > 0; j >>= 1) {
            for (int i = tid; i < n; i += NTHR2) {
                int l = i ^ j;
                if (l > i) {
                    float vi = cval[i], vl = cval[l];
                    int   ii = cidx[i], il = cidx[l];
                    bool lFirst = (vl > vi) || (vl == vi && il < ii);
                    bool asc = ((i & k) == 0);
                    if (lFirst == asc) {
                        cval[i] = vl; cval[l] = vi;
                        cidx[i] = il; cidx[l] = ii;
                    }
                }
            }
            __syncthreads();
        }
    }

    // ---- parallel softmax terms; serial decision is add/compare-only ----
    for (int i = tid; i < C; i += NTHR2)
        rbuf[i] = expf(cval[i] - M) / Z;
    __syncthreads();

    if (tid == 0) {
        float cum = 0.0f;
        int m = 0;
        float vp = cval[min(49, C - 1)];
        for (int i = 0; i < C; ++i) {
            cum += rbuf[i];
            if (i > 0 && cum > topp) break;      // suffix removed; m final
            m = i;
            if (m >= 49 && cval[i] < vp) break;  // past pivot tie-run
        }
        int send;
        if (m >= 49) {
            int e = 49;
            while (e + 1 < C && cval[e + 1] == vp) ++e;
            send = (m < e) ? m : e;
        } else {
            send = m;
        }
        sSend = send;
    }
    __syncthreads();

    // ---- final softmax over support, scatter, sample ----
    const int send = sSend;
    const float v0 = cval[0];
    for (int i = tid; i <= send; i += NTHR2)
        rbuf[i] = expf(cval[i] / temp - v0 / temp);
    __syncthreads();
    if (tid == 0) {
        float S = 0.0f;
        for (int i = 0; i <= send; ++i) S += rbuf[i];
        sS = S;
    }
    __syncthreads();
    const float S = sS;

    float bestr = -1.0f;
    int   besti = 0x7FFFFFFF;
    for (int i = tid; i <= send; i += NTHR2) {
        float p = rbuf[i] / S;
        int v = cidx[i];
        orow[v] = p;                             // memset + scratch re-zero did the rest
        float q = -logf(urow[v]);
        float r = p / q;
        if (r > bestr || (r == bestr && v < besti)) { bestr = r; besti = v; }
    }
    for (int off = 32; off; off >>= 1) {
        float r2 = __shfl_down(bestr, off);
        int   i2 = __shfl_down(besti, off);
        if (r2 > bestr || (r2 == bestr && i2 < besti)) { bestr = r2; besti = i2; }
    }
    if (lane == 0) { redf[wid] = bestr; redi[wid] = besti; }
    __syncthreads();
    if (tid == 0) {
        float br = redf[0]; int bi = redi[0];
        for (int i = 1; i < NWAVE2; ++i) {
            if (redf[i] > br || (redf[i] == br && redi[i] < bi)) { br = redf[i]; bi = redi[i]; }
        }
        out[row] = (float)bi;
    }
}

extern "C" void kernel_launch(void* const* d_in, const int* in_sizes, int n_in,
                              void* d_out, int out_size, void* d_ws, size_t ws_size,
                              hipStream_t stream) {
    const float* logits = (const float*)d_in[0];
    const int*   prev   = (const int*)d_in[1];
    const float* rand_u = (const float*)d_in[2];
    const float* tempp  = (const float*)d_in[3];
    const float* toppp  = (const float*)d_in[4];
    const float* repp   = (const float*)d_in[5];
    float* out = (float*)d_out;

    // out_size is in BYTES (rocprof: the old out_size*sizeof(float) memset
    // wrote 4.117e8 B = 4x the 102,930,432-B buffer). Zero exactly the buffer.
    (void)hipMemsetAsync(d_out, 0, (size_t)out_size, stream);

    hipLaunchKernelGGL(pass1_kernel, dim3(B_SIZE), dim3(NTHR1), 0, stream,
                       logits, prev, repp, out);
    hipLaunchKernelGGL(decide_kernel, dim3(B_SIZE), dim3(NTHR2), 0, stream,
                       logits, prev, rand_u, tempp, toppp, repp, out);
}

// Round 6
// 252.869 us; speedup vs baseline: 1.0720x; 1.0109x over previous
//
#include <hip/hip_runtime.h>
#include <cstdint>
#include <cmath>

#define V_SIZE 50257
#define T_SIZE 2048
#define B_SIZE 512
#define CAND_MAX 1024
#define SPEC_THRESH 10.0f
#define SPEC_MIN 80
#define KOFF 32.0f

#define NTHR 1024
#define NWAVE (NTHR / 64)

#define BM_WORDS ((V_SIZE + 31) / 32)

// ---------------------------------------------------------------------------
// Fused kernel (split attribution round done; fusion removes the inter-kernel
// drain + the 4.2MB scratch round-trip + decide's scratch re-zero).
//   phase 1: prev bitmap + dedup'd expsum correction (penalty off hot path)
//   phase 2: pure stream: plain expsum + speculative candidates (x > 10)
//   phase 3: fix penalties on candidates; M from candidates; Z from corrected sum
//   phase 4: bitonic sort — REGISTER/shfl_xor for j<64 (no barriers), LDS only
//            for j>=64: 45 barriers -> ~12 at n=512. Same comparator, same order.
//   phase 5: top-p/top-k decision (serial, order-preserving), softmax, scatter,
//            gumbel-argmax sample.
// Bisection fallback (~never) self-contained, reuses the phase-1 bitmap.
// ---------------------------------------------------------------------------
extern "C" __global__ __launch_bounds__(NTHR, 8)
void fused_kernel(const float* __restrict__ logits,
                  const int*   __restrict__ prev,
                  const float* __restrict__ rand_u,
                  const float* __restrict__ tempp,
                  const float* __restrict__ toppp,
                  const float* __restrict__ repp,
                  float* __restrict__ out)
{
    const int row  = blockIdx.x;
    const int tid  = threadIdx.x;
    const int lane = tid & 63;
    const int wid  = tid >> 6;

    __shared__ unsigned int bitmap[BM_WORDS];
    __shared__ float cval[CAND_MAX];
    __shared__ int   cidx[CAND_MAX];
    __shared__ float rbuf[CAND_MAX];
    __shared__ float redf[NWAVE];
    __shared__ float redm[NWAVE];
    __shared__ int   redi[NWAVE];
    __shared__ float sM, sZ, sS, sStot;
    __shared__ int   sCnt, sSend;

    const float rp   = repp[0];
    const float topp = toppp[0];
    const float temp = fmaxf(tempp[0], 1e-5f);

    const size_t rowoff = (size_t)row * V_SIZE;
    const float* lrow = logits + rowoff;
    const float* urow = rand_u + rowoff;
    float*       orow = out + B_SIZE + rowoff;

    // ---- init LDS ----
    for (int i = tid; i < BM_WORDS; i += NTHR) bitmap[i] = 0u;
    if (tid == 0) sCnt = 0;
    __syncthreads();

    // ---- phase 1: prev bitmap + dedup'd correction ----
    const int* prow = prev + (size_t)row * T_SIZE;
    float corr = 0.0f;
    for (int i = tid; i < T_SIZE; i += NTHR) {
        int v = prow[i];
        unsigned bit = 1u << (v & 31);
        unsigned old = atomicOr(&bitmap[((unsigned)v) >> 5], bit);
        if (!(old & bit)) {                    // first setter owns the correction
            float x  = lrow[v];
            float xp = (x < 0.0f) ? x * rp : x / rp;
            corr += __expf(xp - KOFF) - __expf(x - KOFF);
        }
    }

    // ---- phase 2: plain stream (no bitmap reads, no penalty, no max) ----
    const int head  = (4 - (row & 3)) & 3;     // V%4==1 -> row*V mod 4 == row mod 4
    const int nvec  = (V_SIZE - head) >> 2;
    const int tails = head + nvec * 4;
    const float4* lrow4 = (const float4*)(lrow + head);

    float lz0 = 0.0f, lz1 = 0.0f;
    auto collect = [&](float x, int v) {
        if (x > SPEC_THRESH) {
            int p = atomicAdd(&sCnt, 1);
            if (p < CAND_MAX) { cval[p] = x; cidx[p] = v; }
        }
    };
    if (tid < head) {
        float x = lrow[tid];
        collect(x, tid);
        lz0 += __expf(x - KOFF);
    }
    if (tid < V_SIZE - tails) {
        float x = lrow[tails + tid];
        collect(x, tails + tid);
        lz0 += __expf(x - KOFF);
    }
    for (int i = tid; i < nvec; i += NTHR) {
        float4 x4 = lrow4[i];
        int v = head + i * 4;
        collect(x4.x, v);     collect(x4.y, v + 1);
        collect(x4.z, v + 2); collect(x4.w, v + 3);
        lz0 += __expf(x4.x - KOFF) + __expf(x4.z - KOFF);
        lz1 += __expf(x4.y - KOFF) + __expf(x4.w - KOFF);
    }
    __syncthreads();                           // bitmap + candidate list complete

    // ---- phase 3: fix candidate penalties; reduce sum; M over candidates ----
    const int Craw = sCnt;
    int C = min(Craw, CAND_MAX);
    for (int i = tid; i < C; i += NTHR) {
        int v = cidx[i];
        if ((bitmap[((unsigned)v) >> 5] >> (v & 31)) & 1u) {
            float x = cval[i];
            cval[i] = (x < 0.0f) ? x * rp : x / rp;
        }
    }
    {
        float wz = lz0 + lz1 + corr;
        for (int off = 32; off; off >>= 1) wz += __shfl_down(wz, off);
        if (lane == 0) redf[wid] = wz;
    }
    __syncthreads();                           // cval fixed + redf ready

    {
        float lm = -INFINITY;
        for (int i = tid; i < C; i += NTHR) lm = fmaxf(lm, cval[i]);
        for (int off = 32; off; off >>= 1) lm = fmaxf(lm, __shfl_down(lm, off));
        if (lane == 0) redm[wid] = lm;
    }
    __syncthreads();
    if (tid == 0) {
        float s = 0.0f, m = -INFINITY;
        for (int i = 0; i < NWAVE; ++i) { s += redf[i]; m = fmaxf(m, redm[i]); }
        sStot = s; sM = m;
    }
    __syncthreads();

    float M = sM;
    float Z = sStot * expf(KOFF - M);
    // exactness of the speculative path requires: count in range AND the fixed
    // candidate max clears the plain threshold (=> true row max is a candidate).
    bool ok = (Craw >= SPEC_MIN && Craw <= CAND_MAX && M > SPEC_THRESH);

    if (!ok) {
        // ---- fallback: full recompute with penalty inline (≈never);
        //      bitmap already built in phase 1 ----
        float lm = -INFINITY, lz = 0.0f;
        for (int v = tid; v < V_SIZE; v += NTHR) {
            float x = lrow[v];
            if ((bitmap[((unsigned)v) >> 5] >> (v & 31)) & 1u)
                x = (x < 0.0f) ? x * rp : x / rp;
            lm = fmaxf(lm, x);
            lz += __expf(x - KOFF);
        }
        {
            float wm = lm;
            for (int off = 32; off; off >>= 1) wm = fmaxf(wm, __shfl_down(wm, off));
            if (lane == 0) redm[wid] = wm;
        }
        __syncthreads();
        if (tid == 0) {
            float m = redm[0];
            for (int i = 1; i < NWAVE; ++i) m = fmaxf(m, redm[i]);
            sM = m;
        }
        __syncthreads();
        M = sM;
        {
            float wz = lz;
            for (int off = 32; off; off >>= 1) wz += __shfl_down(wz, off);
            if (lane == 0) redf[wid] = wz;
        }
        __syncthreads();
        if (tid == 0) {
            float s = 0.0f;
            for (int i = 0; i < NWAVE; ++i) s += redf[i];
            sZ = s * expf(KOFF - M);
        }
        __syncthreads();
        Z = sZ;

        auto count_pass = [&](float thr) -> int {
            __syncthreads();
            if (tid == 0) sCnt = 0;
            __syncthreads();
            int local = 0;
            for (int v = tid; v < V_SIZE; v += NTHR) {
                float x = lrow[v];
                if ((bitmap[((unsigned)v) >> 5] >> (v & 31)) & 1u)
                    x = (x < 0.0f) ? x * rp : x / rp;
                if (x > thr) local++;
            }
            if (local) atomicAdd(&sCnt, local);
            __syncthreads();
            return sCnt;
        };
        float a = -200.0f, b = 200.0f, thr = 0.0f;
        int c = 0;
        for (int it = 0; it < 40; ++it) {
            thr = 0.5f * (a + b);
            c = count_pass(thr);
            if (c < SPEC_MIN)       b = thr;
            else if (c > CAND_MAX)  a = thr;
            else break;
        }
        if (c < SPEC_MIN) thr = a;
        __syncthreads();
        if (tid == 0) sCnt = 0;
        __syncthreads();
        for (int v = tid; v < V_SIZE; v += NTHR) {
            float x = lrow[v];
            if ((bitmap[((unsigned)v) >> 5] >> (v & 31)) & 1u)
                x = (x < 0.0f) ? x * rp : x / rp;
            if (x > thr) {
                int p = atomicAdd(&sCnt, 1);
                if (p < CAND_MAX) { cval[p] = x; cidx[p] = v; }
            }
        }
        __syncthreads();
        C = min(sCnt, CAND_MAX);
    }

    // ---- phase 4: bitonic sort, descending value, tie -> ascending index ----
    int n = 1; while (n < C) n <<= 1;          // n in [128,1024]; typ. 512
    for (int i = C + tid; i < n; i += NTHR) { cval[i] = -INFINITY; cidx[i] = 0x7FFFFFFF; }
    __syncthreads();

    if (n <= 512) {
        // register-resident: element t lives in thread t; shfl_xor for j<64
        // (partner in same wave since n is a multiple of 64), LDS for j>=64.
        // 'act' is wave-uniform, so barriers stay outside the guard and shfl
        // never runs on a partial wave.
        const int t = tid;
        const bool act = (t < n);
        float v = 0.0f; int id = 0;
        if (act) { v = cval[t]; id = cidx[t]; }
        for (int k = 2; k <= n; k <<= 1) {
            for (int j = k >> 1; j > 0; j >>= 1) {
                float pv = 0.0f; int pid = 0;
                if (j >= 64) {
                    __syncthreads();           // prior reads of cval/cidx done
                    if (act) { cval[t] = v; cidx[t] = id; }
                    __syncthreads();
                    if (act) { pv = cval[t ^ j]; pid = cidx[t ^ j]; }
                } else if (act) {
                    pv  = __shfl_xor(v, j);
                    pid = __shfl_xor(id, j);
                }
                if (act) {
                    const bool amLow = ((t & j) == 0);
                    const float vi = amLow ? v : pv,  vl = amLow ? pv : v;
                    const int   ii = amLow ? id : pid, il = amLow ? pid : id;
                    const bool lFirst = (vl > vi) || (vl == vi && il < ii);
                    const bool asc = ((t & k) == 0);
                    if (lFirst == asc) { v = pv; id = pid; }   // both take partner's
                }
            }
        }
        __syncthreads();
        if (act) { cval[t] = v; cidx[t] = id; }
        __syncthreads();
    } else {
        // n = 1024 (C > 512, ≈never): original LDS bitonic
        for (int k = 2; k <= n; k <<= 1) {
            for (int j = k >> 1; j > 0; j >>= 1) {
                for (int i = tid; i < n; i += NTHR) {
                    int l = i ^ j;
                    if (l > i) {
                        float vi = cval[i], vl = cval[l];
                        int   ii = cidx[i], il = cidx[l];
                        bool lFirst = (vl > vi) || (vl == vi && il < ii);
                        bool asc = ((i & k) == 0);
                        if (lFirst == asc) {
                            cval[i] = vl; cval[l] = vi;
                            cidx[i] = il; cidx[l] = ii;
                        }
                    }
                }
                __syncthreads();
            }
        }
    }

    // ---- phase 5: decision (serial, order-preserving), softmax, scatter ----
    for (int i = tid; i < C; i += NTHR)
        rbuf[i] = expf(cval[i] - M) / Z;
    __syncthreads();

    if (tid == 0) {
        float cum = 0.0f;
        int m = 0;
        float vp = cval[min(49, C - 1)];
        for (int i = 0; i < C; ++i) {
            cum += rbuf[i];
            if (i > 0 && cum > topp) break;      // suffix removed; m final
            m = i;
            if (m >= 49 && cval[i] < vp) break;  // past pivot tie-run
        }
        int send;
        if (m >= 49) {
            int e = 49;
            while (e + 1 < C && cval[e + 1] == vp) ++e;
            send = (m < e) ? m : e;
        } else {
            send = m;
        }
        sSend = send;
    }
    __syncthreads();

    const int send = sSend;
    const float v0 = cval[0];
    for (int i = tid; i <= send; i += NTHR)
        rbuf[i] = expf(cval[i] / temp - v0 / temp);
    __syncthreads();
    if (tid == 0) {
        float S = 0.0f;
        for (int i = 0; i <= send; ++i) S += rbuf[i];
        sS = S;
    }
    __syncthreads();
    const float S = sS;

    float bestr = -1.0f;
    int   besti = 0x7FFFFFFF;
    for (int i = tid; i <= send; i += NTHR) {
        float p = rbuf[i] / S;
        int v = cidx[i];
        orow[v] = p;                             // memset provided the zeros
        float q = -logf(urow[v]);
        float r = p / q;
        if (r > bestr || (r == bestr && v < besti)) { bestr = r; besti = v; }
    }
    for (int off = 32; off; off >>= 1) {
        float r2 = __shfl_down(bestr, off);
        int   i2 = __shfl_down(besti, off);
        if (r2 > bestr || (r2 == bestr && i2 < besti)) { bestr = r2; besti = i2; }
    }
    if (lane == 0) { redf[wid] = bestr; redi[wid] = besti; }
    __syncthreads();
    if (tid == 0) {
        float br = redf[0]; int bi = redi[0];
        for (int i = 1; i < NWAVE; ++i) {
            if (redf[i] > br || (redf[i] == br && redi[i] < bi)) { br = redf[i]; bi = redi[i]; }
        }
        out[row] = (float)bi;                    // idx as f32 (exact for < 2^24)
    }
}

extern "C" void kernel_launch(void* const* d_in, const int* in_sizes, int n_in,
                              void* d_out, int out_size, void* d_ws, size_t ws_size,
                              hipStream_t stream) {
    const float* logits = (const float*)d_in[0];
    const int*   prev   = (const int*)d_in[1];
    const float* rand_u = (const float*)d_in[2];
    const float* tempp  = (const float*)d_in[3];
    const float* toppp  = (const float*)d_in[4];
    const float* repp   = (const float*)d_in[5];
    float* out = (float*)d_out;

    // Unchanged from the passing R5 config (don't perturb the memset in the
    // same round as a kernel restructure).
    (void)hipMemsetAsync(d_out, 0, (size_t)out_size, stream);

    hipLaunchKernelGGL(fused_kernel, dim3(B_SIZE), dim3(NTHR), 0, stream,
                       logits, prev, rand_u, tempp, toppp, repp, out);
}